// Round 17
// baseline (209.435 us; speedup 1.0000x reference)
//
#include <hip/hip_runtime.h>
#include <math.h>

// No FMA contraction: decision path rounds every op individually.
#pragma clang fp contract(off)

#define B 8
#define SP2 262144   // 512*512
#define SP3 65536    // 256*256

// ws float-indexed layout:
//  [0, 4194304)            imga f64 [8,512,512]        (K1->K3)
//  [4194304, 6291456)      codes uchar4 [8,512,512]    (K3 ->K6)
//  [6291456, 8912896)      maskq u8 [8,5,512,512]      (K6 -> K7F)
//  [10485760, 15728640)    rcs f64 [24,512,7]          (K1->K25)
//  [20971520, ...)         tail: thrLo 32 | thrHi 32 | ghist 816 | pmn 1280 f | pmx 1280 f
#define POOLF  4194304
#define MASKQF 6291456
#define TRIHF  10485760
#define TAILF  20971520

// ---------------- K1: 3x3 s2 avgpool (f64) + channel mean + fused per-row sublattice sums ----
// Block = 2 full rows (all 3 channels), XCD-swizzled so adjacent rows share L2.
__global__ void k1_pool3(const float* __restrict__ x, double* __restrict__ imga,
                         double* __restrict__ rcs) {
    __shared__ double redE[2][3][128], redO[2][3][128];
    __shared__ double edge[2][3][5];   // col0, col1, col509, col510, col511
    int blk = (blockIdx.x & 7) * 256 + (blockIdx.x >> 3);   // bijective, nwg=2048
    int tid = threadIdx.x;
    int q = tid & 127;                 // quad: outputs xo = 4q .. 4q+3
    int r = tid >> 7;                  // row-in-block
    int rowIdx = blk * 2 + r;          // [0, 4096)
    int yo = rowIdx & 511;
    int b  = rowIdx >> 9;
    int xb = 8 * q;
    double pv[3][4];
    for (int c = 0; c < 3; ++c) {
        const float* p = x + ((size_t)(b * 3 + c)) * 1048576;
        double s0 = 0.0, s1 = 0.0, s2 = 0.0, s3 = 0.0;
        #pragma unroll
        for (int dy = 0; dy < 3; ++dy) {
            int iy = 2 * yo - 1 + dy;
            if ((unsigned)iy >= 1024u) continue;
            const float* row = p + (size_t)iy * 1024 + xb;
            float4 fM = *(const float4*)row;
            float4 fR = *(const float4*)(row + 4);
            float  vm1 = (q > 0) ? row[-1] : 0.f;
            s0 += (double)vm1  + (double)fM.x + (double)fM.y;
            s1 += (double)fM.y + (double)fM.z + (double)fM.w;
            s2 += (double)fM.w + (double)fR.x + (double)fR.y;
            s3 += (double)fR.y + (double)fR.z + (double)fR.w;
        }
        pv[c][0] = s0 * (1.0 / 9.0); pv[c][1] = s1 * (1.0 / 9.0);
        pv[c][2] = s2 * (1.0 / 9.0); pv[c][3] = s3 * (1.0 / 9.0);
        redE[r][c][q] = pv[c][0] + pv[c][2];
        redO[r][c][q] = pv[c][1] + pv[c][3];
        if (q == 0)   { edge[r][c][0] = pv[c][0]; edge[r][c][1] = pv[c][1]; }
        if (q == 127) { edge[r][c][2] = pv[c][1]; edge[r][c][3] = pv[c][2]; edge[r][c][4] = pv[c][3]; }
    }
    double* ia = imga + (size_t)b * SP2 + yo * 512 + 4 * q;
    #pragma unroll
    for (int k = 0; k < 4; ++k)
        ia[k] = ((pv[0][k] + pv[1][k]) + pv[2][k]) * (1.0 / 3.0);
    __syncthreads();
    for (int s = 64; s > 0; s >>= 1) {
        if (q < s) {
            #pragma unroll
            for (int c = 0; c < 3; ++c) {
                redE[r][c][q] += redE[r][c][q + s];
                redO[r][c][q] += redO[r][c][q + s];
            }
        }
        __syncthreads();
    }
    if (q < 21) {
        int c = q / 7, kx = q - c * 7;
        double E = redE[r][c][0], O = redO[r][c][0];
        double val;
        switch (kx) {
            case 0: val = O - edge[r][c][2] - edge[r][c][4]; break;  // odd <=507
            case 1: val = E - edge[r][c][3]; break;                  // even <=508
            case 2: val = O - edge[r][c][4]; break;                  // odd <=509
            case 3: val = E; break;                                  // all even
            case 4: val = O; break;                                  // all odd
            case 5: val = E - edge[r][c][0]; break;                  // even >=2
            default: val = O - edge[r][c][1]; break;                 // odd >=3
        }
        rcs[((size_t)(b * 3 + c) * 512 + yo) * 7 + kx] = val;
    }
}

// ---------------- K3: GL conv (f64) -> crisp + fuzzed bin codes ----------------
__global__ void k3_gl(const double* __restrict__ imga, const float* __restrict__ weight,
                      uchar4* __restrict__ codes) {
    __shared__ double xv[101];
    for (int i = threadIdx.x; i < 101; i += 256) {
        double d = (double)i / 100.0;
        xv[i] = (double)(float)(10.0 * d * d * d);
    }
    __syncthreads();
    int idx = blockIdx.x * 256 + threadIdx.x;
    int xo = idx & 511;
    int yo = (idx >> 9) & 511;
    int b  = idx >> 18;
    const double* im = imga + (size_t)b * SP2;
    double GL = (double)weight[0];
    double a1 = GL * 4.0, a2 = -a1 / 8.0, a3 = -a1 / 16.0;
    auto g = [&](int y, int x) -> double {
        if ((unsigned)y >= 512u || (unsigned)x >= 512u) return 0.0;
        return im[y * 512 + x];
    };
    double v = a1 * g(yo, xo)
             + a2 * (g(yo - 1, xo) + g(yo, xo - 1) + g(yo, xo + 1) + g(yo + 1, xo))
             + a3 * (g(yo - 2, xo) + g(yo - 1, xo - 1) + g(yo - 1, xo + 1) + g(yo, xo - 2)
                   + g(yo, xo + 2) + g(yo + 1, xo - 1) + g(yo + 1, xo + 1) + g(yo + 2, xo));
    double t = fabs(v);
    const double EPS = 6e-7;
    int cM;
    if (t < 1e-6) cM = 255;
    else if (t > xv[100]) cM = 101;
    else {
        int lo = 0, hi = 100;
        while (lo < hi) { int mid = (lo + hi) >> 1; if (t <= xv[mid]) hi = mid; else lo = mid + 1; }
        cM = lo;
    }
    double ua = t - EPS;
    int cA;
    if (ua < 1e-6) cA = 255;
    else if (ua > xv[100]) cA = 101;
    else {
        int k = (cM == 101) ? 100 : ((cM == 255) ? 100 : cM);
        while (k > 0 && ua <= xv[k - 1]) --k;
        cA = k;
    }
    double ub = t + EPS;
    int cB;
    if (ub < 1e-6) cB = 255;
    else if (ub > xv[100]) cB = 101;
    else {
        int k = (cM == 255) ? 0 : ((cM == 101) ? 100 : cM);
        while (k < 100 && ub > xv[k]) ++k;
        cB = k;
    }
    codes[idx] = make_uchar4((unsigned char)cM, (unsigned char)cA, (unsigned char)cB, 0);
}

// ---------------- K4: per-batch crisp-code histogram, uint4 loads (4 px/iter) ----------------
__global__ void k4_hist(const uchar4* __restrict__ codes, int* __restrict__ ghist) {
    int b = blockIdx.y;
    __shared__ int h[102];
    for (int i = threadIdx.x; i < 102; i += 256) h[i] = 0;
    __syncthreads();
    const uint4* cb = (const uint4*)(codes + (size_t)b * SP2);
    for (int p = blockIdx.x * 256 + threadIdx.x; p < SP2 / 4; p += 64 * 256) {
        uint4 v = cb[p];
        int c0 = v.x & 255, c1 = v.y & 255, c2 = v.z & 255, c3 = v.w & 255;
        if (c0 != 255) atomicAdd(&h[c0], 1);
        if (c1 != 255) atomicAdd(&h[c1], 1);
        if (c2 != 255) atomicAdd(&h[c2], 1);
        if (c3 != 255) atomicAdd(&h[c3], 1);
    }
    __syncthreads();
    for (int i = threadIdx.x; i < 102; i += 256)
        if (h[i]) atomicAdd(&ghist[b * 102 + i], h[i]);
}

// ---------------- K25: conv-sums (bit-identical to old k2b) + targets + argmin hedge --------
__global__ void k25_thr(const double* __restrict__ rcs, const float* __restrict__ convw,
                        const int* __restrict__ ghist,
                        const float* __restrict__ bn_gamma, const float* __restrict__ bn_beta,
                        const float* __restrict__ bn_mean, const float* __restrict__ bn_var,
                        int* __restrict__ thrLo, int* __restrict__ thrHi) {
    int b = blockIdx.x;
    int t = threadIdx.x;            // 256 threads; t = oy for the conv part
    __shared__ double red[256];
    __shared__ double ps[4];
    for (int oi = 0; oi < 4; ++oi) {
        int o = oi + 1;
        double acc = 0.0;
        #pragma unroll 7
        for (int tap = 0; tap < 147; ++tap) {
            int c = tap / 49;
            int k = tap - c * 49;
            int ky = k / 7, kx = k - ky * 7;
            int iy = 2 * t + ky - 3;
            if ((unsigned)iy < 512u) {
                double w = (double)convw[o * 147 + tap];
                acc += w * rcs[((size_t)(b * 3 + c) * 512 + iy) * 7 + kx];
            }
        }
        red[t] = acc;
        __syncthreads();
        for (int s2 = 128; s2 > 0; s2 >>= 1) {
            if (t < s2) red[t] += red[t + s2];
            __syncthreads();
        }
        if (t == 0) {
            double m = red[0] / 65536.0;
            double scale = (double)bn_gamma[o] / sqrt((double)bn_var[o] + 1e-5);
            double val = (m - (double)bn_mean[o]) * scale + (double)bn_beta[o];
            const double base[4] = {0.2, 0.4, 0.6, 0.8};
            ps[oi] = base[oi] + 0.05 * tanh(val);
        }
        __syncthreads();
    }
    __shared__ int    hS[102];
    __shared__ int    cumI[101];
    __shared__ double pct[101];
    __shared__ int    allS;
    if (t < 102) hS[t] = ghist[b * 102 + t];
    __syncthreads();
    if (t == 0) {
        int all = 0;
        for (int k = 0; k < 102; ++k) all += hS[k];
        allS = all;
        int cum = 0;
        for (int k = 0; k < 101; ++k) { cum += hS[k]; cumI[k] = cum; }
        for (int i = 0; i < 4; ++i)
            for (int j = i + 1; j < 4; ++j)
                if (ps[j] < ps[i]) { double tp = ps[i]; ps[i] = ps[j]; ps[j] = tp; }
    }
    __syncthreads();
    double alld = (double)allS;
    if (t < 101) pct[t] = (double)cumI[t] / alld;
    __syncthreads();
    if (t < 4) {
        const double EPS_TIE = 1.2e-7;
        double target = ps[t];
        double best = 1e300; int bi = 0;
        for (int k = 0; k < 101; ++k) {
            double z = fabs(pct[k] - target);
            if (z < best) { best = z; bi = k; }   // strict < => first occurrence
        }
        int lo = bi, hi = bi;
        for (int k = 0; k < 101; ++k) {
            double z = fabs(pct[k] - target);
            if (z <= best + EPS_TIE) { if (k < lo) lo = k; if (k > hi) hi = k; }
        }
        int cnt = cumI[hi] - cumI[lo];
        if (cnt > 2) { lo = bi; hi = bi; }
        thrLo[b * 4 + t] = lo;
        thrHi[b * 4 + t] = hi;
    }
}

// ---------------- K6: quarter-unit band mask, 4 pixels/thread, uchar4 stores ----------------
__global__ void k6_mask(const uchar4* __restrict__ codes, const int* __restrict__ thrLo,
                        const int* __restrict__ thrHi, unsigned char* __restrict__ mq) {
    int idx4 = blockIdx.x * 256 + threadIdx.x;  // quad index, [0, 524288)
    int b  = idx4 >> 16;
    int sp0 = (idx4 & 65535) * 4;
    const uchar4* cb = codes + (size_t)b * SP2 + sp0;
    uchar4 cd[4] = {cb[0], cb[1], cb[2], cb[3]};
    const int* tL = thrLo + b * 4;
    const int* tH = thrHi + b * 4;
    int t0L = tL[0], t1L = tL[1], t2L = tL[2], t3L = tL[3];
    int t0H = tH[0], t1H = tH[1], t2H = tH[2], t3H = tH[3];
    unsigned char wv[5][4];
    #pragma unroll
    for (int px = 0; px < 4; ++px) {
        int w0 = 0, w1 = 0, w2 = 0, w3 = 0, w4 = 0;
        int cand[2] = {cd[px].y, cd[px].z};
        #pragma unroll
        for (int ci = 0; ci < 2; ++ci) {
            int c = cand[ci];
            if (c == 255) continue;
            if (c <= t0L) ++w0; else if (c <= t1L) ++w1; else if (c <= t2L) ++w2;
            else if (c <= t3L) ++w3; else ++w4;
            if (c <= t0H) ++w0; else if (c <= t1H) ++w1; else if (c <= t2H) ++w2;
            else if (c <= t3H) ++w3; else ++w4;
        }
        wv[0][px] = (unsigned char)w0; wv[1][px] = (unsigned char)w1;
        wv[2][px] = (unsigned char)w2; wv[3][px] = (unsigned char)w3;
        wv[4][px] = (unsigned char)w4;
    }
    unsigned char* mb = mq + (size_t)b * 5 * SP2 + sp0;
    #pragma unroll
    for (int pl = 0; pl < 5; ++pl)
        *(uchar4*)(mb + (size_t)pl * SP2) = make_uchar4(wv[pl][0], wv[pl][1], wv[pl][2], wv[pl][3]);
}

// ---------------- K7F: fused pool chain, 512 threads (deeper stage parallelism) -------------
__global__ void __launch_bounds__(512) k7f(const unsigned char* __restrict__ mq,
                                           float* __restrict__ out,
                                           float* __restrict__ pmn, float* __restrict__ pmx) {
    __shared__ unsigned short shH[39][512];    // triH rows; later aliased triV
    __shared__ unsigned short shB[31][512];    // boxV rows; later aliased h2(int)
    __shared__ float smn[512], smx[512];
    unsigned short (*shT)[512] = shH;
    int (*shD)[256] = (int (*)[256])shB;

    int blk = (blockIdx.x & 7) * 160 + (blockIdx.x >> 3);   // bijective XCD swizzle, nwg=1280
    int g  = blk & 31;
    int ch = blk >> 5;
    int y0 = g * 8;
    int tid = threadIdx.x;
    int lane = tid & 63;
    int rsel = tid >> 6;               // 0..7

    // ---- Stage A: horizontal 17-tap triangle for 39 rows -> shH (8 rows in parallel) ----
    for (int it = 0; it < 5; ++it) {
        int rl = 8 * it + rsel;
        if (rl >= 39) break;
        int gr = 2 * y0 - 12 + rl;
        int x0 = lane * 8;
        uint4 pk = make_uint4(0u, 0u, 0u, 0u);
        if ((unsigned)gr < 512u) {
            const uint2* r8 = (const uint2*)(mq + (size_t)ch * SP2 + (size_t)gr * 512);
            uint2 cL = (lane > 0)  ? r8[lane - 1] : make_uint2(0u, 0u);
            uint2 cM = r8[lane];
            uint2 cR = (lane < 63) ? r8[lane + 1] : make_uint2(0u, 0u);
            int v[24];
            auto unpack = [](uint2 c, int* dst) {
                dst[0] = c.x & 255; dst[1] = (c.x >> 8) & 255; dst[2] = (c.x >> 16) & 255; dst[3] = (c.x >> 24) & 255;
                dst[4] = c.y & 255; dst[5] = (c.y >> 8) & 255; dst[6] = (c.y >> 16) & 255; dst[7] = (c.y >> 24) & 255;
            };
            unpack(cL, v); unpack(cM, v + 8); unpack(cR, v + 16);
            int bx[16];
            int s = 0;
            #pragma unroll
            for (int i = 0; i < 9; ++i) s += v[i];
            bx[0] = s;
            #pragma unroll
            for (int k = 1; k < 16; ++k) { s += v[k + 8] - v[k - 1]; bx[k] = s; }
            if (lane == 0)  { bx[0] = 0; bx[1] = 0; bx[2] = 0; bx[3] = 0; }
            if (lane == 63) { bx[12] = 0; bx[13] = 0; bx[14] = 0; bx[15] = 0; }
            int t = 0;
            #pragma unroll
            for (int i = 0; i < 9; ++i) t += bx[i];
            unsigned short o[8];
            o[0] = (unsigned short)t;
            #pragma unroll
            for (int i = 1; i < 8; ++i) { t += bx[i + 8] - bx[i - 1]; o[i] = (unsigned short)t; }
            pk.x = (unsigned)o[0] | ((unsigned)o[1] << 16);
            pk.y = (unsigned)o[2] | ((unsigned)o[3] << 16);
            pk.z = (unsigned)o[4] | ((unsigned)o[5] << 16);
            pk.w = (unsigned)o[6] | ((unsigned)o[7] << 16);
        }
        *(uint4*)&shH[rl][x0] = pk;
    }
    __syncthreads();

    // ---- Stage B: vertical box9 for 31 center rows -> shB (single pass, x = tid) ----
    {
        int x = tid;
        int s = 0;
        #pragma unroll
        for (int i = 0; i < 9; ++i) s += (int)shH[i][x];
        int j0 = 2 * y0 - 8;
        unsigned short bv[31];
        bv[0] = (unsigned short)(((unsigned)j0 < 512u) ? s : 0);
        #pragma unroll
        for (int jl = 1; jl < 31; ++jl) {
            s += (int)shH[jl + 8][x] - (int)shH[jl - 1][x];
            int j = j0 + jl;
            bv[jl] = (unsigned short)(((unsigned)j < 512u) ? s : 0);
        }
        #pragma unroll
        for (int jl = 0; jl < 31; ++jl) shB[jl][x] = bv[jl];
    }
    __syncthreads();

    // ---- Stage C: vertical box9 of shB -> triV (23 rows) into shT (aliases shH) ----
    {
        int x = tid;
        int s = 0;
        #pragma unroll
        for (int i = 0; i < 9; ++i) s += (int)shB[i][x];
        unsigned short tv[23];
        tv[0] = (unsigned short)s;
        #pragma unroll
        for (int rl = 1; rl < 23; ++rl) {
            s += (int)shB[rl + 8][x] - (int)shB[rl - 1][x];
            tv[rl] = (unsigned short)s;
        }
        // writes go to shT(=shH); reads were from shB only -> no conflict, no barrier needed
        #pragma unroll
        for (int rl = 0; rl < 23; ++rl) shT[rl][x] = tv[rl];
    }
    __syncthreads();

    // ---- Stage D: horizontal box9 stride-2 -> shD (23 x 256 int, aliases shB) ----
    for (int it = 0; it < 3; ++it) {
        int rl = 8 * it + rsel;
        if (rl >= 23) break;
        int gr = 2 * y0 - 4 + rl;
        int ox0 = lane * 4;
        int o0 = 0, o1 = 0, o2 = 0, o3 = 0;
        if ((unsigned)gr < 512u) {
            int v[15];
            #pragma unroll
            for (int i = 0; i < 15; ++i) {
                int ix = 2 * ox0 - 4 + i;
                v[i] = ((unsigned)ix < 512u) ? (int)shT[rl][ix] : 0;
            }
            int s = 0;
            #pragma unroll
            for (int i = 0; i < 9; ++i) s += v[i];
            o0 = s;
            s += v[9] + v[10] - v[0] - v[1];   o1 = s;
            s += v[11] + v[12] - v[2] - v[3];  o2 = s;
            s += v[13] + v[14] - v[4] - v[5];  o3 = s;
        }
        shD[rl][ox0] = o0; shD[rl][ox0 + 1] = o1; shD[rl][ox0 + 2] = o2; shD[rl][ox0 + 3] = o3;
    }
    __syncthreads();

    // ---- Stage E: vertical box9 stride-2 -> out (2 row-groups in parallel), min/max ----
    int x = tid & 255;
    int dy0 = (tid >> 8) * 4;          // 0 or 4
    float lmn = 3.4e38f, lmx = -3.4e38f;
    float* op = out + (size_t)ch * SP3 + (size_t)y0 * 256 + x;
    #pragma unroll
    for (int k = 0; k < 4; ++k) {
        int dy = dy0 + k;
        int s = 0;
        #pragma unroll
        for (int d = 0; d < 9; ++d) s += shD[2 * dy + d][x];
        float val = (float)s / 2125764.0f;   // 4 * 81^3
        op[(size_t)dy * 256] = val;
        lmn = fminf(lmn, val); lmx = fmaxf(lmx, val);
    }
    smn[tid] = lmn; smx[tid] = lmx;
    __syncthreads();
    for (int st = 256; st > 0; st >>= 1) {
        if (tid < st) {
            smn[tid] = fminf(smn[tid], smn[tid + st]);
            smx[tid] = fmaxf(smx[tid], smx[tid + st]);
        }
        __syncthreads();
    }
    if (tid == 0) { pmn[blk] = smn[0]; pmx[blk] = smx[0]; }
}

// ---------------- K9: normalize, with in-block reduce of the 32 per-channel partials --------
__global__ void k9_norm(float* __restrict__ o, const float* __restrict__ pmn,
                        const float* __restrict__ pmx) {
    __shared__ float sm[2];
    int idx = blockIdx.x * 256 + threadIdx.x;
    int ch = idx >> 16;                       // 256 blocks per channel
    int lane = threadIdx.x & 63;
    if (threadIdx.x < 64) {
        float v = (lane < 32) ? pmn[ch * 32 + lane] : pmx[ch * 32 + (lane - 32)];
        #pragma unroll
        for (int off = 16; off > 0; off >>= 1) {
            float u = __shfl_xor(v, off, 64);
            v = (lane < 32) ? fminf(v, u) : fmaxf(v, u);
        }
        if (lane == 0)  sm[0] = v;
        if (lane == 32) sm[1] = v;
    }
    __syncthreads();
    float a = sm[0];
    float bmax = sm[1];
    o[idx] = (o[idx] - a) / (bmax - a);
}

extern "C" void kernel_launch(void* const* d_in, const int* in_sizes, int n_in,
                              void* d_out, int out_size, void* d_ws, size_t ws_size,
                              hipStream_t stream) {
    const float* x      = (const float*)d_in[0];
    const float* weight = (const float*)d_in[1];
    const float* conv_w = (const float*)d_in[2];
    const float* bn_g   = (const float*)d_in[3];
    const float* bn_b   = (const float*)d_in[4];
    const float* bn_m   = (const float*)d_in[5];
    const float* bn_v   = (const float*)d_in[6];
    float* out = (float*)d_out;
    float* ws  = (float*)d_ws;

    double* imga   = (double*)ws;
    uchar4* codes  = (uchar4*)(ws + POOLF);
    unsigned char* maskq = (unsigned char*)(ws + MASKQF);
    double* rcs    = (double*)(ws + TRIHF);
    int*    thrLo   = (int*)(ws + TAILF);
    int*    thrHi   = thrLo + 32;
    int*    ghist   = thrHi + 32;
    float*  pmn     = (float*)(ghist + 816);           // 1280
    float*  pmx     = pmn + 1280;                      // 1280

    hipMemsetAsync(ghist, 0, 816 * sizeof(int), stream);

    k1_pool3  <<<2048, 256, 0, stream>>>(x, imga, rcs);
    k3_gl     <<<8192, 256, 0, stream>>>(imga, weight, codes);
    k4_hist   <<<dim3(64, B), 256, 0, stream>>>(codes, ghist);
    k25_thr   <<<B, 256, 0, stream>>>(rcs, conv_w, ghist, bn_g, bn_b, bn_m, bn_v, thrLo, thrHi);
    k6_mask   <<<2048, 256, 0, stream>>>(codes, thrLo, thrHi, maskq);
    k7f       <<<1280, 512, 0, stream>>>(maskq, out, pmn, pmx);
    k9_norm   <<<10240, 256, 0, stream>>>(out, pmn, pmx);
}

// Round 18
// 118.331 us; speedup vs baseline: 1.7699x; 1.7699x over previous
//
#include <hip/hip_runtime.h>
#include <math.h>

// No FMA contraction: decision path rounds every op individually.
#pragma clang fp contract(off)

#define B 8
#define SP2 262144   // 512*512
#define SP3 65536    // 256*256

// ws float-indexed layout:
//  [0, 4194304)            imga f64 [8,512,512]        (K1->K3)
//  [4194304, 6291456)      codes uchar4 [8,512,512]    (K3 ->K6)
//  [6291456, 8912896)      maskq u8 [8,5,512,512]      (K6 -> K7F)
//  [10485760, 15728640)    rcs f64 [24,512,7]          (K1->KS)
//  [20971520, ...)         tail: S 1176 dbl | thrLo 32 | thrHi 32 | ghist 816 | pmn 1280 | pmx 1280
#define POOLF  4194304
#define MASKQF 6291456
#define TRIHF  10485760
#define TAILF  20971520

// ---------------- K1: 3x3 s2 avgpool (f64) + channel mean + fused per-row sublattice sums ----
__global__ void k1_pool3(const float* __restrict__ x, double* __restrict__ imga,
                         double* __restrict__ rcs) {
    __shared__ double redE[2][3][128], redO[2][3][128];
    __shared__ double edge[2][3][5];   // col0, col1, col509, col510, col511
    int blk = (blockIdx.x & 7) * 256 + (blockIdx.x >> 3);   // bijective, nwg=2048
    int tid = threadIdx.x;
    int q = tid & 127;                 // quad: outputs xo = 4q .. 4q+3
    int r = tid >> 7;                  // row-in-block
    int rowIdx = blk * 2 + r;          // [0, 4096)
    int yo = rowIdx & 511;
    int b  = rowIdx >> 9;
    int xb = 8 * q;
    double pv[3][4];
    for (int c = 0; c < 3; ++c) {
        const float* p = x + ((size_t)(b * 3 + c)) * 1048576;
        double s0 = 0.0, s1 = 0.0, s2 = 0.0, s3 = 0.0;
        #pragma unroll
        for (int dy = 0; dy < 3; ++dy) {
            int iy = 2 * yo - 1 + dy;
            if ((unsigned)iy >= 1024u) continue;
            const float* row = p + (size_t)iy * 1024 + xb;
            float4 fM = *(const float4*)row;
            float4 fR = *(const float4*)(row + 4);
            float  vm1 = (q > 0) ? row[-1] : 0.f;
            s0 += (double)vm1  + (double)fM.x + (double)fM.y;
            s1 += (double)fM.y + (double)fM.z + (double)fM.w;
            s2 += (double)fM.w + (double)fR.x + (double)fR.y;
            s3 += (double)fR.y + (double)fR.z + (double)fR.w;
        }
        pv[c][0] = s0 * (1.0 / 9.0); pv[c][1] = s1 * (1.0 / 9.0);
        pv[c][2] = s2 * (1.0 / 9.0); pv[c][3] = s3 * (1.0 / 9.0);
        redE[r][c][q] = pv[c][0] + pv[c][2];
        redO[r][c][q] = pv[c][1] + pv[c][3];
        if (q == 0)   { edge[r][c][0] = pv[c][0]; edge[r][c][1] = pv[c][1]; }
        if (q == 127) { edge[r][c][2] = pv[c][1]; edge[r][c][3] = pv[c][2]; edge[r][c][4] = pv[c][3]; }
    }
    double* ia = imga + (size_t)b * SP2 + yo * 512 + 4 * q;
    #pragma unroll
    for (int k = 0; k < 4; ++k)
        ia[k] = ((pv[0][k] + pv[1][k]) + pv[2][k]) * (1.0 / 3.0);
    __syncthreads();
    for (int s = 64; s > 0; s >>= 1) {
        if (q < s) {
            #pragma unroll
            for (int c = 0; c < 3; ++c) {
                redE[r][c][q] += redE[r][c][q + s];
                redO[r][c][q] += redO[r][c][q + s];
            }
        }
        __syncthreads();
    }
    if (q < 21) {
        int c = q / 7, kx = q - c * 7;
        double E = redE[r][c][0], O = redO[r][c][0];
        double val;
        switch (kx) {
            case 0: val = O - edge[r][c][2] - edge[r][c][4]; break;
            case 1: val = E - edge[r][c][3]; break;
            case 2: val = O - edge[r][c][4]; break;
            case 3: val = E; break;
            case 4: val = O; break;
            case 5: val = E - edge[r][c][0]; break;
            default: val = O - edge[r][c][1]; break;
        }
        rcs[((size_t)(b * 3 + c) * 512 + yo) * 7 + kx] = val;
    }
}

// ---------------- KS: S(b,c,ky,kx) = sum_oy rcs[b,c,2oy+ky-3,kx]  (168 blocks, coalesced) ----
__global__ void kS(const double* __restrict__ rcs, double* __restrict__ S) {
    int blk = blockIdx.x;          // bc*7 + ky
    int ky = blk % 7;
    int bc = blk / 7;
    int t = threadIdx.x;           // oy
    double v[7] = {0, 0, 0, 0, 0, 0, 0};
    int iy = 2 * t + ky - 3;
    if ((unsigned)iy < 512u) {
        const double* p = rcs + ((size_t)bc * 512 + iy) * 7;
        #pragma unroll
        for (int kx = 0; kx < 7; ++kx) v[kx] = p[kx];
    }
    __shared__ double red[7][256];
    #pragma unroll
    for (int kx = 0; kx < 7; ++kx) red[kx][t] = v[kx];
    __syncthreads();
    for (int s = 128; s > 0; s >>= 1) {
        if (t < s) {
            #pragma unroll
            for (int kx = 0; kx < 7; ++kx)
                red[kx][t] += red[kx][t + s];
        }
        __syncthreads();
    }
    if (t < 7) S[(size_t)blk * 7 + t] = red[t][0];
}

// ---------------- K3: GL conv (f64) -> crisp + fuzzed bin codes ----------------
__global__ void k3_gl(const double* __restrict__ imga, const float* __restrict__ weight,
                      uchar4* __restrict__ codes) {
    __shared__ double xv[101];
    for (int i = threadIdx.x; i < 101; i += 256) {
        double d = (double)i / 100.0;
        xv[i] = (double)(float)(10.0 * d * d * d);
    }
    __syncthreads();
    int idx = blockIdx.x * 256 + threadIdx.x;
    int xo = idx & 511;
    int yo = (idx >> 9) & 511;
    int b  = idx >> 18;
    const double* im = imga + (size_t)b * SP2;
    double GL = (double)weight[0];
    double a1 = GL * 4.0, a2 = -a1 / 8.0, a3 = -a1 / 16.0;
    auto g = [&](int y, int x) -> double {
        if ((unsigned)y >= 512u || (unsigned)x >= 512u) return 0.0;
        return im[y * 512 + x];
    };
    double v = a1 * g(yo, xo)
             + a2 * (g(yo - 1, xo) + g(yo, xo - 1) + g(yo, xo + 1) + g(yo + 1, xo))
             + a3 * (g(yo - 2, xo) + g(yo - 1, xo - 1) + g(yo - 1, xo + 1) + g(yo, xo - 2)
                   + g(yo, xo + 2) + g(yo + 1, xo - 1) + g(yo + 1, xo + 1) + g(yo + 2, xo));
    double t = fabs(v);
    const double EPS = 6e-7;
    int cM;
    if (t < 1e-6) cM = 255;
    else if (t > xv[100]) cM = 101;
    else {
        int lo = 0, hi = 100;
        while (lo < hi) { int mid = (lo + hi) >> 1; if (t <= xv[mid]) hi = mid; else lo = mid + 1; }
        cM = lo;
    }
    double ua = t - EPS;
    int cA;
    if (ua < 1e-6) cA = 255;
    else if (ua > xv[100]) cA = 101;
    else {
        int k = (cM == 101) ? 100 : ((cM == 255) ? 100 : cM);
        while (k > 0 && ua <= xv[k - 1]) --k;
        cA = k;
    }
    double ub = t + EPS;
    int cB;
    if (ub < 1e-6) cB = 255;
    else if (ub > xv[100]) cB = 101;
    else {
        int k = (cM == 255) ? 0 : ((cM == 101) ? 100 : cM);
        while (k < 100 && ub > xv[k]) ++k;
        cB = k;
    }
    codes[idx] = make_uchar4((unsigned char)cM, (unsigned char)cA, (unsigned char)cB, 0);
}

// ---------------- K4: per-batch crisp-code histogram, uint4 loads ----------------
__global__ void k4_hist(const uchar4* __restrict__ codes, int* __restrict__ ghist) {
    int b = blockIdx.y;
    __shared__ int h[102];
    for (int i = threadIdx.x; i < 102; i += 256) h[i] = 0;
    __syncthreads();
    const uint4* cb = (const uint4*)(codes + (size_t)b * SP2);
    for (int p = blockIdx.x * 256 + threadIdx.x; p < SP2 / 4; p += 64 * 256) {
        uint4 v = cb[p];
        int c0 = v.x & 255, c1 = v.y & 255, c2 = v.z & 255, c3 = v.w & 255;
        if (c0 != 255) atomicAdd(&h[c0], 1);
        if (c1 != 255) atomicAdd(&h[c1], 1);
        if (c2 != 255) atomicAdd(&h[c2], 1);
        if (c3 != 255) atomicAdd(&h[c3], 1);
    }
    __syncthreads();
    for (int i = threadIdx.x; i < 102; i += 256)
        if (h[i]) atomicAdd(&ghist[b * 102 + i], h[i]);
}

// ---------------- K5: targets from S (tiny dot) + argmin with near-tie hedge ----------------
__global__ void k5_thr(const double* __restrict__ S, const float* __restrict__ convw,
                       const int* __restrict__ ghist,
                       const float* __restrict__ bn_gamma, const float* __restrict__ bn_beta,
                       const float* __restrict__ bn_mean, const float* __restrict__ bn_var,
                       int* __restrict__ thrLo, int* __restrict__ thrHi) {
    int b = blockIdx.x;
    int t = threadIdx.x;            // 128 threads
    __shared__ int    hS[102];
    __shared__ int    cumI[101];
    __shared__ double pct[101];
    __shared__ double ps[4];
    __shared__ int    allS;
    if (t < 102) hS[t] = ghist[b * 102 + t];
    if (t < 4) {
        int o = t + 1;
        double acc = 0.0;
        #pragma unroll 7
        for (int tap = 0; tap < 147; ++tap) {
            int c = tap / 49;
            int k = tap - c * 49;
            int ky = k / 7, kx = k - ky * 7;
            acc += (double)convw[o * 147 + tap] * S[(((size_t)(b * 3 + c)) * 7 + ky) * 7 + kx];
        }
        double m = acc / 65536.0;
        double scale = (double)bn_gamma[o] / sqrt((double)bn_var[o] + 1e-5);
        double val = (m - (double)bn_mean[o]) * scale + (double)bn_beta[o];
        const double base[4] = {0.2, 0.4, 0.6, 0.8};
        ps[t] = base[t] + 0.05 * tanh(val);
    }
    __syncthreads();
    if (t == 0) {
        int all = 0;
        for (int k = 0; k < 102; ++k) all += hS[k];
        allS = all;
        int cum = 0;
        for (int k = 0; k < 101; ++k) { cum += hS[k]; cumI[k] = cum; }
        for (int i = 0; i < 4; ++i)
            for (int j = i + 1; j < 4; ++j)
                if (ps[j] < ps[i]) { double tp = ps[i]; ps[i] = ps[j]; ps[j] = tp; }
    }
    __syncthreads();
    double alld = (double)allS;
    if (t < 101) pct[t] = (double)cumI[t] / alld;
    __syncthreads();
    if (t < 4) {
        const double EPS_TIE = 1.2e-7;
        double target = ps[t];
        double best = 1e300; int bi = 0;
        for (int k = 0; k < 101; ++k) {
            double z = fabs(pct[k] - target);
            if (z < best) { best = z; bi = k; }   // strict < => first occurrence
        }
        int lo = bi, hi = bi;
        for (int k = 0; k < 101; ++k) {
            double z = fabs(pct[k] - target);
            if (z <= best + EPS_TIE) { if (k < lo) lo = k; if (k > hi) hi = k; }
        }
        int cnt = cumI[hi] - cumI[lo];
        if (cnt > 2) { lo = bi; hi = bi; }
        thrLo[b * 4 + t] = lo;
        thrHi[b * 4 + t] = hi;
    }
}

// ---------------- K6: quarter-unit band mask, 4 pixels/thread, uchar4 stores ----------------
__global__ void k6_mask(const uchar4* __restrict__ codes, const int* __restrict__ thrLo,
                        const int* __restrict__ thrHi, unsigned char* __restrict__ mq) {
    int idx4 = blockIdx.x * 256 + threadIdx.x;
    int b  = idx4 >> 16;
    int sp0 = (idx4 & 65535) * 4;
    const uchar4* cb = codes + (size_t)b * SP2 + sp0;
    uchar4 cd[4] = {cb[0], cb[1], cb[2], cb[3]};
    const int* tL = thrLo + b * 4;
    const int* tH = thrHi + b * 4;
    int t0L = tL[0], t1L = tL[1], t2L = tL[2], t3L = tL[3];
    int t0H = tH[0], t1H = tH[1], t2H = tH[2], t3H = tH[3];
    unsigned char wv[5][4];
    #pragma unroll
    for (int px = 0; px < 4; ++px) {
        int w0 = 0, w1 = 0, w2 = 0, w3 = 0, w4 = 0;
        int cand[2] = {cd[px].y, cd[px].z};
        #pragma unroll
        for (int ci = 0; ci < 2; ++ci) {
            int c = cand[ci];
            if (c == 255) continue;
            if (c <= t0L) ++w0; else if (c <= t1L) ++w1; else if (c <= t2L) ++w2;
            else if (c <= t3L) ++w3; else ++w4;
            if (c <= t0H) ++w0; else if (c <= t1H) ++w1; else if (c <= t2H) ++w2;
            else if (c <= t3H) ++w3; else ++w4;
        }
        wv[0][px] = (unsigned char)w0; wv[1][px] = (unsigned char)w1;
        wv[2][px] = (unsigned char)w2; wv[3][px] = (unsigned char)w3;
        wv[4][px] = (unsigned char)w4;
    }
    unsigned char* mb = mq + (size_t)b * 5 * SP2 + sp0;
    #pragma unroll
    for (int pl = 0; pl < 5; ++pl)
        *(uchar4*)(mb + (size_t)pl * SP2) = make_uchar4(wv[pl][0], wv[pl][1], wv[pl][2], wv[pl][3]);
}

// ---------------- K7F: fused pool chain, 512 threads ----------------
__global__ void __launch_bounds__(512) k7f(const unsigned char* __restrict__ mq,
                                           float* __restrict__ out,
                                           float* __restrict__ pmn, float* __restrict__ pmx) {
    __shared__ unsigned short shH[39][512];
    __shared__ unsigned short shB[31][512];
    __shared__ float smn[512], smx[512];
    unsigned short (*shT)[512] = shH;
    int (*shD)[256] = (int (*)[256])shB;

    int blk = (blockIdx.x & 7) * 160 + (blockIdx.x >> 3);   // bijective XCD swizzle, nwg=1280
    int g  = blk & 31;
    int ch = blk >> 5;
    int y0 = g * 8;
    int tid = threadIdx.x;
    int lane = tid & 63;
    int rsel = tid >> 6;               // 0..7

    for (int it = 0; it < 5; ++it) {
        int rl = 8 * it + rsel;
        if (rl >= 39) break;
        int gr = 2 * y0 - 12 + rl;
        int x0 = lane * 8;
        uint4 pk = make_uint4(0u, 0u, 0u, 0u);
        if ((unsigned)gr < 512u) {
            const uint2* r8 = (const uint2*)(mq + (size_t)ch * SP2 + (size_t)gr * 512);
            uint2 cL = (lane > 0)  ? r8[lane - 1] : make_uint2(0u, 0u);
            uint2 cM = r8[lane];
            uint2 cR = (lane < 63) ? r8[lane + 1] : make_uint2(0u, 0u);
            int v[24];
            auto unpack = [](uint2 c, int* dst) {
                dst[0] = c.x & 255; dst[1] = (c.x >> 8) & 255; dst[2] = (c.x >> 16) & 255; dst[3] = (c.x >> 24) & 255;
                dst[4] = c.y & 255; dst[5] = (c.y >> 8) & 255; dst[6] = (c.y >> 16) & 255; dst[7] = (c.y >> 24) & 255;
            };
            unpack(cL, v); unpack(cM, v + 8); unpack(cR, v + 16);
            int bx[16];
            int s = 0;
            #pragma unroll
            for (int i = 0; i < 9; ++i) s += v[i];
            bx[0] = s;
            #pragma unroll
            for (int k = 1; k < 16; ++k) { s += v[k + 8] - v[k - 1]; bx[k] = s; }
            if (lane == 0)  { bx[0] = 0; bx[1] = 0; bx[2] = 0; bx[3] = 0; }
            if (lane == 63) { bx[12] = 0; bx[13] = 0; bx[14] = 0; bx[15] = 0; }
            int t = 0;
            #pragma unroll
            for (int i = 0; i < 9; ++i) t += bx[i];
            unsigned short o[8];
            o[0] = (unsigned short)t;
            #pragma unroll
            for (int i = 1; i < 8; ++i) { t += bx[i + 8] - bx[i - 1]; o[i] = (unsigned short)t; }
            pk.x = (unsigned)o[0] | ((unsigned)o[1] << 16);
            pk.y = (unsigned)o[2] | ((unsigned)o[3] << 16);
            pk.z = (unsigned)o[4] | ((unsigned)o[5] << 16);
            pk.w = (unsigned)o[6] | ((unsigned)o[7] << 16);
        }
        *(uint4*)&shH[rl][x0] = pk;
    }
    __syncthreads();

    {
        int x = tid;
        int s = 0;
        #pragma unroll
        for (int i = 0; i < 9; ++i) s += (int)shH[i][x];
        int j0 = 2 * y0 - 8;
        unsigned short bv[31];
        bv[0] = (unsigned short)(((unsigned)j0 < 512u) ? s : 0);
        #pragma unroll
        for (int jl = 1; jl < 31; ++jl) {
            s += (int)shH[jl + 8][x] - (int)shH[jl - 1][x];
            int j = j0 + jl;
            bv[jl] = (unsigned short)(((unsigned)j < 512u) ? s : 0);
        }
        #pragma unroll
        for (int jl = 0; jl < 31; ++jl) shB[jl][x] = bv[jl];
    }
    __syncthreads();

    {
        int x = tid;
        int s = 0;
        #pragma unroll
        for (int i = 0; i < 9; ++i) s += (int)shB[i][x];
        unsigned short tv[23];
        tv[0] = (unsigned short)s;
        #pragma unroll
        for (int rl = 1; rl < 23; ++rl) {
            s += (int)shB[rl + 8][x] - (int)shB[rl - 1][x];
            tv[rl] = (unsigned short)s;
        }
        #pragma unroll
        for (int rl = 0; rl < 23; ++rl) shT[rl][x] = tv[rl];
    }
    __syncthreads();

    for (int it = 0; it < 3; ++it) {
        int rl = 8 * it + rsel;
        if (rl >= 23) break;
        int gr = 2 * y0 - 4 + rl;
        int ox0 = lane * 4;
        int o0 = 0, o1 = 0, o2 = 0, o3 = 0;
        if ((unsigned)gr < 512u) {
            int v[15];
            #pragma unroll
            for (int i = 0; i < 15; ++i) {
                int ix = 2 * ox0 - 4 + i;
                v[i] = ((unsigned)ix < 512u) ? (int)shT[rl][ix] : 0;
            }
            int s = 0;
            #pragma unroll
            for (int i = 0; i < 9; ++i) s += v[i];
            o0 = s;
            s += v[9] + v[10] - v[0] - v[1];   o1 = s;
            s += v[11] + v[12] - v[2] - v[3];  o2 = s;
            s += v[13] + v[14] - v[4] - v[5];  o3 = s;
        }
        shD[rl][ox0] = o0; shD[rl][ox0 + 1] = o1; shD[rl][ox0 + 2] = o2; shD[rl][ox0 + 3] = o3;
    }
    __syncthreads();

    int x = tid & 255;
    int dy0 = (tid >> 8) * 4;
    float lmn = 3.4e38f, lmx = -3.4e38f;
    float* op = out + (size_t)ch * SP3 + (size_t)y0 * 256 + x;
    #pragma unroll
    for (int k = 0; k < 4; ++k) {
        int dy = dy0 + k;
        int s = 0;
        #pragma unroll
        for (int d = 0; d < 9; ++d) s += shD[2 * dy + d][x];
        float val = (float)s / 2125764.0f;
        op[(size_t)dy * 256] = val;
        lmn = fminf(lmn, val); lmx = fmaxf(lmx, val);
    }
    smn[tid] = lmn; smx[tid] = lmx;
    __syncthreads();
    for (int st = 256; st > 0; st >>= 1) {
        if (tid < st) {
            smn[tid] = fminf(smn[tid], smn[tid + st]);
            smx[tid] = fmaxf(smx[tid], smx[tid + st]);
        }
        __syncthreads();
    }
    if (tid == 0) { pmn[blk] = smn[0]; pmx[blk] = smx[0]; }
}

// ---------------- K9: normalize, with in-block reduce of the 32 per-channel partials --------
__global__ void k9_norm(float* __restrict__ o, const float* __restrict__ pmn,
                        const float* __restrict__ pmx) {
    __shared__ float sm[2];
    int idx = blockIdx.x * 256 + threadIdx.x;
    int ch = idx >> 16;
    int lane = threadIdx.x & 63;
    if (threadIdx.x < 64) {
        float v = (lane < 32) ? pmn[ch * 32 + lane] : pmx[ch * 32 + (lane - 32)];
        #pragma unroll
        for (int off = 16; off > 0; off >>= 1) {
            float u = __shfl_xor(v, off, 64);
            v = (lane < 32) ? fminf(v, u) : fmaxf(v, u);
        }
        if (lane == 0)  sm[0] = v;
        if (lane == 32) sm[1] = v;
    }
    __syncthreads();
    float a = sm[0];
    float bmax = sm[1];
    o[idx] = (o[idx] - a) / (bmax - a);
}

extern "C" void kernel_launch(void* const* d_in, const int* in_sizes, int n_in,
                              void* d_out, int out_size, void* d_ws, size_t ws_size,
                              hipStream_t stream) {
    const float* x      = (const float*)d_in[0];
    const float* weight = (const float*)d_in[1];
    const float* conv_w = (const float*)d_in[2];
    const float* bn_g   = (const float*)d_in[3];
    const float* bn_b   = (const float*)d_in[4];
    const float* bn_m   = (const float*)d_in[5];
    const float* bn_v   = (const float*)d_in[6];
    float* out = (float*)d_out;
    float* ws  = (float*)d_ws;

    double* imga   = (double*)ws;
    uchar4* codes  = (uchar4*)(ws + POOLF);
    unsigned char* maskq = (unsigned char*)(ws + MASKQF);
    double* rcs    = (double*)(ws + TRIHF);
    double* S       = (double*)(ws + TAILF);           // 1176 doubles = 2352 floats
    int*    thrLo   = (int*)(ws + TAILF + 2368);
    int*    thrHi   = thrLo + 32;
    int*    ghist   = thrHi + 32;
    float*  pmn     = (float*)(ghist + 816);           // 1280
    float*  pmx     = pmn + 1280;                      // 1280

    hipMemsetAsync(ghist, 0, 816 * sizeof(int), stream);

    k1_pool3  <<<2048, 256, 0, stream>>>(x, imga, rcs);
    kS        <<<168, 256, 0, stream>>>(rcs, S);
    k3_gl     <<<8192, 256, 0, stream>>>(imga, weight, codes);
    k4_hist   <<<dim3(64, B), 256, 0, stream>>>(codes, ghist);
    k5_thr    <<<B, 128, 0, stream>>>(S, conv_w, ghist, bn_g, bn_b, bn_m, bn_v, thrLo, thrHi);
    k6_mask   <<<2048, 256, 0, stream>>>(codes, thrLo, thrHi, maskq);
    k7f       <<<1280, 512, 0, stream>>>(maskq, out, pmn, pmx);
    k9_norm   <<<10240, 256, 0, stream>>>(out, pmn, pmx);
}